// Round 1
// baseline (480.369 us; speedup 1.0000x reference)
//
#include <hip/hip_runtime.h>

// (B,T,D,H,KD)=(8,1024,512,8,64), SIGMA=1.
// d_out: out [8*1024*512] f32, then attn_weights [64][1024][1024] f32.
// R5: 2-phase prefetch double-buffer (T3-minimum) in all GEMMs and flash
// (1 barrier/K-step, stage latency hidden under compute).  Flash drops the
// V LDS staging (V is L2-resident per-XCD; B-frags read global->reg).
// q2/k2 fused into q/k GEMM epilogues.  Coalesced LDS-tile wt_cvt.

typedef float  floatx4 __attribute__((ext_vector_type(4)));
typedef short  short8  __attribute__((ext_vector_type(8)));
typedef unsigned short ushort_t;

#define MFMA16(a, b, c) __builtin_amdgcn_mfma_f32_16x16x32_bf16((a), (b), (c), 0, 0, 0)

__device__ inline ushort_t f2b(float f) {  // f32 -> bf16 bits, RNE
    unsigned u = __builtin_bit_cast(unsigned, f);
    unsigned r = u + 0x7fffu + ((u >> 16) & 1u);
    return (ushort_t)(r >> 16);
}
__device__ inline ushort_t f2b_trunc(float f) {
    return (ushort_t)(__builtin_bit_cast(unsigned, f) >> 16);
}
__device__ inline float b2f(ushort_t s) {
    return __builtin_bit_cast(float, (unsigned)s << 16);
}

// Async global->LDS, 16B per lane.  LDS dest = wave-uniform base + lane*16.
__device__ inline void gl_lds16(const void* g, void* l) {
    __builtin_amdgcn_global_load_lds(
        (const __attribute__((address_space(1))) unsigned int*)g,
        (__attribute__((address_space(3))) unsigned int*)l, 16, 0, 0);
}

// ---------------------------------------------------------------------------
// Weight transpose + split via LDS tile (coalesced both sides):
// WT[n][k] = W[k][n]; hi=bf16(w), lo=bf16(w-hi).
// grid (64 tiles, 4 weights), 256 threads; tile = 64(k) x 64(n).
// ---------------------------------------------------------------------------
__global__ __launch_bounds__(256) void wt_cvt(
    const float* __restrict__ Wq, const float* __restrict__ Wk,
    const float* __restrict__ Wv, const float* __restrict__ Wo,
    ushort_t* __restrict__ qTh, ushort_t* __restrict__ qTl,
    ushort_t* __restrict__ kTh, ushort_t* __restrict__ kTl,
    ushort_t* __restrict__ vT,  ushort_t* __restrict__ oT)
{
    __shared__ float sT[64][65];
    const int tid = threadIdx.x;
    const int c = tid & 63, rq = tid >> 6;
    const int bx = blockIdx.x;
    const int k0 = (bx >> 3) * 64, n0 = (bx & 7) * 64;

    const float* W; ushort_t* H; ushort_t* L; bool wl;
    switch (blockIdx.y) {
        case 0:  W = Wq; H = qTh; L = qTl; wl = true;  break;
        case 1:  W = Wk; H = kTh; L = kTl; wl = true;  break;
        case 2:  W = Wv; H = vT;  L = vT;  wl = false; break;
        default: W = Wo; H = oT;  L = oT;  wl = false; break;
    }

#pragma unroll
    for (int i = 0; i < 16; ++i) {
        const int row = i * 4 + rq;                      // k within tile
        sT[row][c] = W[(size_t)(k0 + row) * 512 + n0 + c];
    }
    __syncthreads();
#pragma unroll
    for (int i = 0; i < 16; ++i) {
        const int nrow = i * 4 + rq;                     // n within tile
        const float f = sT[c][nrow];                     // bank-conflict-free
        const ushort_t h = f2b(f);
        const size_t o = (size_t)(n0 + nrow) * 512 + k0 + c;
        H[o] = h;
        if (wl) L[o] = f2b(f - b2f(h));
    }
}

// ---------------------------------------------------------------------------
// LDS-staged MFMA GEMM, K=512, tile 64x64, BK=32, 256 threads (4 waves,
// wave w owns rows 16w..16w+15 x all 64 cols).  grid = 1024: mt=gid>>3,
// nt=gid&7 (gid%8 = n-panel -> per-XCD B locality).
// 2-phase prefetch: double-buffered LDS, stage(it+1) issued before compute(it),
// single barrier/iter (its vmcnt(0) drain overlaps the whole compute phase).
// AT=float: A fp32 staged raw, hi/lo split after LDS read (NPASS=3 uses lo).
// AT=ushort_t: A bf16.  OUTMODE 0: f32.  1: bf16 hi+lo (+ fused row-norms ->
// normOut[z][t], the 64-col n-panel is exactly one head).  2: vhT[z][d][T].
// Chunk swizzle: LDS slot = (chunk + row) % nchunks -> conflict-free reads.
// ---------------------------------------------------------------------------
template <typename AT, int NPASS, int OUTMODE>
__global__ __launch_bounds__(256) void gemm_lds(
    const AT* __restrict__ A, const ushort_t* __restrict__ BTh,
    const ushort_t* __restrict__ BTl, float* __restrict__ outF,
    ushort_t* __restrict__ outH, ushort_t* __restrict__ outL,
    float* __restrict__ normOut)
{
    constexpr bool AF = (sizeof(AT) == 4);
    __shared__ __align__(16) float    sAf[AF ? 2 * 64 * 32 : 4];   // fp32 A dbuf
    __shared__ __align__(16) ushort_t sAb[AF ? 8 : 2 * 64 * 32];   // bf16 A dbuf
    __shared__ __align__(16) ushort_t sBh[2 * 64 * 32];
    __shared__ __align__(16) ushort_t sBl[NPASS == 3 ? 2 * 64 * 32 : 8];

    const int tid = threadIdx.x;
    const int w = tid >> 6, lane = tid & 63;
    const int l15 = lane & 15, quad = lane >> 4;
    const int gid = blockIdx.x;
    const int m0 = (gid >> 3) * 64, n0 = (gid & 7) * 64;

    auto STAGE = [&](int bi, int it) {
        const int k0 = it * 32;
        if constexpr (AF) {
            // A tile 64x32 f32 = 8KB: rows of 8 chunks, swizzled.
#pragma unroll
            for (int t = 0; t < 2; ++t) {
                const int c = (w * 2 + t) * 64 + lane;
                const int row = c >> 3, slot = c & 7, kch = (slot - row) & 7;
                gl_lds16((const float*)A + (size_t)(m0 + row) * 512 + k0 + kch * 4,
                         (char*)sAf + (size_t)bi * 8192 + (size_t)(w * 2 + t) * 1024);
            }
        } else {
            // A tile 64x32 bf16 = 4KB: rows of 4 chunks.
            const int c = w * 64 + lane;
            const int row = c >> 2, slot = c & 3, kch = (slot - row) & 3;
            gl_lds16((const ushort_t*)A + (size_t)(m0 + row) * 512 + k0 + kch * 8,
                     (char*)sAb + (size_t)bi * 4096 + (size_t)w * 1024);
        }
        {
            const int c = w * 64 + lane;
            const int row = c >> 2, slot = c & 3, kch = (slot - row) & 3;
            const size_t ge = (size_t)(n0 + row) * 512 + k0 + kch * 8;
            gl_lds16(BTh + ge, (char*)sBh + (size_t)bi * 4096 + (size_t)w * 1024);
            if (NPASS == 3)
                gl_lds16(BTl + ge, (char*)sBl + (size_t)bi * 4096 + (size_t)w * 1024);
        }
    };

    floatx4 acc[4];
#pragma unroll
    for (int i = 0; i < 4; ++i) acc[i] = (floatx4){0.f, 0.f, 0.f, 0.f};

    STAGE(0, 0);
    __syncthreads();
    int cur = 0;

    for (int it = 0; it < 16; ++it) {
        if (it + 1 < 16) STAGE(cur ^ 1, it + 1);   // prefetch, drains at barrier

        const float*    Af = sAf + (size_t)cur * (AF ? 64 * 32 : 0);
        const ushort_t* Ab = sAb + (size_t)cur * (AF ? 0 : 64 * 32);
        const ushort_t* Bh = sBh + (size_t)cur * (64 * 32);
        const ushort_t* Bl = sBl + (size_t)cur * (NPASS == 3 ? 64 * 32 : 0);

        // ---- fragments ----
        short8 ah, al;
        {
            const int row = 16 * w + l15;
            if constexpr (AF) {
                float4 f0 = *(const float4*)&Af[row * 32 + ((quad * 2 + row) & 7) * 4];
                float4 f1 = *(const float4*)&Af[row * 32 + ((quad * 2 + 1 + row) & 7) * 4];
                float fv[8] = {f0.x, f0.y, f0.z, f0.w, f1.x, f1.y, f1.z, f1.w};
#pragma unroll
                for (int j = 0; j < 8; ++j) {
                    ushort_t h = f2b(fv[j]);
                    ah[j] = (short)h;
                    if (NPASS == 3) al[j] = (short)f2b(fv[j] - b2f(h));
                }
            } else {
                ah = *(const short8*)&Ab[row * 32 + ((quad + row) & 3) * 8];
            }
        }
        short8 bh[4], bl[4];
#pragma unroll
        for (int ni = 0; ni < 4; ++ni) {
            const int row = ni * 16 + l15;
            const int off = row * 32 + ((quad + row) & 3) * 8;
            bh[ni] = *(const short8*)&Bh[off];
            if (NPASS == 3) bl[ni] = *(const short8*)&Bl[off];
        }
        // ---- MFMAs ----
#pragma unroll
        for (int ni = 0; ni < 4; ++ni) {
            acc[ni] = MFMA16(ah, bh[ni], acc[ni]);
            if (NPASS == 3) {
                acc[ni] = MFMA16(al, bh[ni], acc[ni]);
                acc[ni] = MFMA16(ah, bl[ni], acc[ni]);
            }
        }
        __syncthreads();
        cur ^= 1;
    }

    // ---- epilogue ----
#pragma unroll
    for (int ni = 0; ni < 4; ++ni) {
        const int n = n0 + ni * 16 + l15;
#pragma unroll
        for (int r = 0; r < 4; ++r) {
            const int m = m0 + 16 * w + quad * 4 + r;
            const float v = acc[ni][r];
            if (OUTMODE == 0) {
                outF[(size_t)m * 512 + n] = v;
            } else if (OUTMODE == 1) {
                ushort_t h = f2b(v);
                outH[(size_t)m * 512 + n] = h;
                outL[(size_t)m * 512 + n] = f2b(v - b2f(h));
            } else {
                const int b = m >> 10, t = m & 1023, hh = n >> 6, d = n & 63;
                outH[((size_t)(b * 8 + hh) * 64 + d) * 1024 + t] = f2b(v);
            }
        }
    }
    if (OUTMODE == 1) {
        // Fused per-head squared norms: cols n0..n0+63 = head (gid&7).
#pragma unroll
        for (int r = 0; r < 4; ++r) {
            float s2 = 0.f;
#pragma unroll
            for (int ni = 0; ni < 4; ++ni) s2 = fmaf(acc[ni][r], acc[ni][r], s2);
#pragma unroll
            for (int off = 1; off < 16; off <<= 1) s2 += __shfl_xor(s2, off);
            if (l15 == 0) {
                const int m = m0 + 16 * w + quad * 4 + r;
                normOut[(size_t)((m >> 10) * 8 + (gid & 7)) * 1024 + (m & 1023)] = s2;
            }
        }
    }
}

// ---------------------------------------------------------------------------
// Fused flash: block = (z, 64 q-rows); gid = qt*64+z so gid%8==h (XCD L2
// locality: each XCD sees one head -> K/V footprint 3MB, L2-resident).
// 2-phase: Khi/Klo double-buffered in LDS, stage(ct+1) issued before
// compute(ct), ONE barrier per tile.  V B-frags read global->reg from L2
// (no sV staging).  QK 3-pass MFMA -> exp -> S store + P LDS strip -> SV.
// ---------------------------------------------------------------------------
__global__ __launch_bounds__(256) void flash_rbf(
    const ushort_t* __restrict__ qh_hi, const ushort_t* __restrict__ qh_lo,
    const ushort_t* __restrict__ kh_hi, const ushort_t* __restrict__ kh_lo,
    const ushort_t* __restrict__ vhT, const float* __restrict__ q2,
    const float* __restrict__ k2, float* __restrict__ S,
    ushort_t* __restrict__ attn)
{
    __shared__ __align__(16) ushort_t sKh[2 * 64 * 64];
    __shared__ __align__(16) ushort_t sKl[2 * 64 * 64];
    __shared__ __align__(16) ushort_t P  [64 * 72];

    const int tid = threadIdx.x;
    const int w = tid >> 6, lane = tid & 63;
    const int l15 = lane & 15, quad = lane >> 4;
    const int gid = blockIdx.x;
    const int z = gid & 63, qt = gid >> 6;
    const int b = z >> 3, h = z & 7;
    const int q0 = qt * 64;

    auto STAGEK = [&](int bi, int ct) {
        const int col0 = ct * 64;
#pragma unroll
        for (int t = 0; t < 2; ++t) {
            const int c = (w * 2 + t) * 64 + lane;
            const int row = c >> 3, slot = c & 7, dch = (slot - row) & 7;
            const size_t ke = (size_t)(b * 1024 + col0 + row) * 512 + h * 64 + dch * 8;
            gl_lds16(kh_hi + ke, (char*)sKh + (size_t)bi * 8192 + (size_t)(w * 2 + t) * 1024);
            gl_lds16(kh_lo + ke, (char*)sKl + (size_t)bi * 8192 + (size_t)(w * 2 + t) * 1024);
        }
    };

    // Q fragments (registers, whole block).
    const size_t qrow = (size_t)(b * 1024 + q0 + 16 * w + l15) * 512 + h * 64 + quad * 8;
    short8 aqh[2], aql[2];
    aqh[0] = *(const short8*)(qh_hi + qrow);
    aqh[1] = *(const short8*)(qh_hi + qrow + 32);
    aql[0] = *(const short8*)(qh_lo + qrow);
    aql[1] = *(const short8*)(qh_lo + qrow + 32);

    float q2v[4];
#pragma unroll
    for (int r = 0; r < 4; ++r)
        q2v[r] = q2[(size_t)z * 1024 + q0 + 16 * w + quad * 4 + r];

    floatx4 oacc[4];
#pragma unroll
    for (int i = 0; i < 4; ++i) oacc[i] = (floatx4){0.f, 0.f, 0.f, 0.f};

    const size_t Sz = (size_t)z << 20;

    STAGEK(0, 0);
    __syncthreads();
    int cur = 0;

    for (int ct = 0; ct < 16; ++ct) {
        const int col0 = ct * 64;

        if (ct + 1 < 16) STAGEK(cur ^ 1, ct + 1);   // prefetch, drains at barrier

        float k2v[4];
#pragma unroll
        for (int j = 0; j < 4; ++j)
            k2v[j] = k2[(size_t)z * 1024 + col0 + j * 16 + l15];

        const ushort_t* Kh = sKh + (size_t)cur * (64 * 64);
        const ushort_t* Kl = sKl + (size_t)cur * (64 * 64);

        // ---- QK^T, 3-pass split ----
        floatx4 s[4];
#pragma unroll
        for (int j = 0; j < 4; ++j) {
            const int row = j * 16 + l15;
            const int base = row * 64;
            short8 kh0 = *(const short8*)&Kh[base + ((quad + row) & 7) * 8];
            short8 kh1 = *(const short8*)&Kh[base + ((quad + 4 + row) & 7) * 8];
            short8 kl0 = *(const short8*)&Kl[base + ((quad + row) & 7) * 8];
            short8 kl1 = *(const short8*)&Kl[base + ((quad + 4 + row) & 7) * 8];
            s[j] = (floatx4){0.f, 0.f, 0.f, 0.f};
            s[j] = MFMA16(aqh[0], kh0, s[j]);
            s[j] = MFMA16(aqh[1], kh1, s[j]);
            s[j] = MFMA16(aql[0], kh0, s[j]);
            s[j] = MFMA16(aql[1], kh1, s[j]);
            s[j] = MFMA16(aqh[0], kl0, s[j]);
            s[j] = MFMA16(aqh[1], kl1, s[j]);
        }

        // ---- V fragments: direct global->reg (L2-resident per-XCD) ----
        short8 gv0[4], gv1[4];
#pragma unroll
        for (int j2 = 0; j2 < 4; ++j2) {
            const size_t vr = ((size_t)z * 64 + j2 * 16 + l15) * 1024 + col0 + quad * 8;
            gv0[j2] = *(const short8*)(vhT + vr);
            gv1[j2] = *(const short8*)(vhT + vr + 32);
        }

        // ---- exp, S store, P pack ----
#pragma unroll
        for (int j = 0; j < 4; ++j) {
#pragma unroll
            for (int r = 0; r < 4; ++r) {
                const float val = __expf(2.f * s[j][r] - q2v[r] - k2v[j]);
                const int row = q0 + 16 * w + quad * 4 + r;
                S[Sz + (size_t)row * 1024 + col0 + j * 16 + l15] = val;
                P[(16 * w + quad * 4 + r) * 72 + j * 16 + l15] = f2b_trunc(val);
            }
        }

        // ---- P readback (A-layout, wave-local) + S@V ----
        short8 pf0 = *(const short8*)&P[(16 * w + l15) * 72 + quad * 8];
        short8 pf1 = *(const short8*)&P[(16 * w + l15) * 72 + 32 + quad * 8];
#pragma unroll
        for (int j2 = 0; j2 < 4; ++j2) {
            oacc[j2] = MFMA16(pf0, gv0[j2], oacc[j2]);
            oacc[j2] = MFMA16(pf1, gv1[j2], oacc[j2]);
        }
        __syncthreads();
        cur ^= 1;
    }

#pragma unroll
    for (int j2 = 0; j2 < 4; ++j2)
#pragma unroll
        for (int r = 0; r < 4; ++r) {
            const int row = q0 + 16 * w + quad * 4 + r;
            attn[(size_t)(b * 1024 + row) * 512 + h * 64 + j2 * 16 + l15] =
                f2b(oacc[j2][r]);
        }
}

extern "C" void kernel_launch(void* const* d_in, const int* in_sizes, int n_in,
                              void* d_out, int out_size, void* d_ws, size_t ws_size,
                              hipStream_t stream)
{
    const float* query = (const float*)d_in[0];
    const float* key   = (const float*)d_in[1];
    const float* value = (const float*)d_in[2];
    const float* Wq    = (const float*)d_in[3];
    const float* Wk    = (const float*)d_in[4];
    const float* Wv    = (const float*)d_in[5];
    const float* Wo    = (const float*)d_in[6];

    float* out  = (float*)d_out;
    float* Sout = out + (size_t)8192 * 512;

    const size_t NE = (size_t)8192 * 512;
    ushort_t* qh_hi   = (ushort_t*)d_ws;
    ushort_t* qh_lo   = qh_hi + NE;
    ushort_t* kh_hi   = qh_lo + NE;
    ushort_t* kh_lo   = kh_hi + NE;
    ushort_t* vhT     = kh_lo + NE;
    ushort_t* attn_bf = vhT + NE;
    ushort_t* WqT_hi  = attn_bf + NE;
    ushort_t* WqT_lo  = WqT_hi + 262144;
    ushort_t* WkT_hi  = WqT_lo + 262144;
    ushort_t* WkT_lo  = WkT_hi + 262144;
    ushort_t* WvT     = WkT_lo + 262144;
    ushort_t* WoT     = WvT + 262144;
    float*    q2      = (float*)(WoT + 262144);
    float*    k2      = q2 + 65536;

    wt_cvt<<<dim3(64, 4), 256, 0, stream>>>(Wq, Wk, Wv, Wo, WqT_hi, WqT_lo,
                                            WkT_hi, WkT_lo, WvT, WoT);

    gemm_lds<float, 3, 1><<<1024, 256, 0, stream>>>(
        query, WqT_hi, WqT_lo, nullptr, qh_hi, qh_lo, q2);
    gemm_lds<float, 3, 1><<<1024, 256, 0, stream>>>(
        key, WkT_hi, WkT_lo, nullptr, kh_hi, kh_lo, k2);
    gemm_lds<float, 1, 2><<<1024, 256, 0, stream>>>(
        value, WvT, nullptr, nullptr, vhT, nullptr, nullptr);

    flash_rbf<<<1024, 256, 0, stream>>>(qh_hi, qh_lo, kh_hi, kh_lo,
                                        vhT, q2, k2, Sout, attn_bf);

    gemm_lds<ushort_t, 1, 0><<<1024, 256, 0, stream>>>(
        attn_bf, WoT, nullptr, out, nullptr, nullptr, nullptr);
}

// Round 2
// 455.307 us; speedup vs baseline: 1.0550x; 1.0550x over previous
//
#include <hip/hip_runtime.h>

// (B,T,D,H,KD)=(8,1024,512,8,64), SIGMA=1.
// d_out: out [8*1024*512] f32, then attn_weights [64][1024][1024] f32.
// R6: flash reverted to R4 form (sV staged, 2 barriers/iter, 33.8KB LDS ->
// 4 blocks/CU; R5's 41.9KB dbuf dropped to 3 blocks/CU = +30us tail).
// Kept from R5: GEMM 2-phase prefetch dbuf, q2/k2 fused into q/k GEMM
// epilogues, coalesced LDS-tile wt_cvt.

typedef float  floatx4 __attribute__((ext_vector_type(4)));
typedef short  short8  __attribute__((ext_vector_type(8)));
typedef unsigned short ushort_t;

#define MFMA16(a, b, c) __builtin_amdgcn_mfma_f32_16x16x32_bf16((a), (b), (c), 0, 0, 0)

__device__ inline ushort_t f2b(float f) {  // f32 -> bf16 bits, RNE
    unsigned u = __builtin_bit_cast(unsigned, f);
    unsigned r = u + 0x7fffu + ((u >> 16) & 1u);
    return (ushort_t)(r >> 16);
}
__device__ inline ushort_t f2b_trunc(float f) {
    return (ushort_t)(__builtin_bit_cast(unsigned, f) >> 16);
}
__device__ inline float b2f(ushort_t s) {
    return __builtin_bit_cast(float, (unsigned)s << 16);
}

// Async global->LDS, 16B per lane.  LDS dest = wave-uniform base + lane*16.
__device__ inline void gl_lds16(const void* g, void* l) {
    __builtin_amdgcn_global_load_lds(
        (const __attribute__((address_space(1))) unsigned int*)g,
        (__attribute__((address_space(3))) unsigned int*)l, 16, 0, 0);
}

// ---------------------------------------------------------------------------
// Weight transpose + split via LDS tile (coalesced both sides):
// WT[n][k] = W[k][n]; hi=bf16(w), lo=bf16(w-hi).
// grid (64 tiles, 4 weights), 256 threads; tile = 64(k) x 64(n).
// ---------------------------------------------------------------------------
__global__ __launch_bounds__(256) void wt_cvt(
    const float* __restrict__ Wq, const float* __restrict__ Wk,
    const float* __restrict__ Wv, const float* __restrict__ Wo,
    ushort_t* __restrict__ qTh, ushort_t* __restrict__ qTl,
    ushort_t* __restrict__ kTh, ushort_t* __restrict__ kTl,
    ushort_t* __restrict__ vT,  ushort_t* __restrict__ oT)
{
    __shared__ float sT[64][65];
    const int tid = threadIdx.x;
    const int c = tid & 63, rq = tid >> 6;
    const int bx = blockIdx.x;
    const int k0 = (bx >> 3) * 64, n0 = (bx & 7) * 64;

    const float* W; ushort_t* H; ushort_t* L; bool wl;
    switch (blockIdx.y) {
        case 0:  W = Wq; H = qTh; L = qTl; wl = true;  break;
        case 1:  W = Wk; H = kTh; L = kTl; wl = true;  break;
        case 2:  W = Wv; H = vT;  L = vT;  wl = false; break;
        default: W = Wo; H = oT;  L = oT;  wl = false; break;
    }

#pragma unroll
    for (int i = 0; i < 16; ++i) {
        const int row = i * 4 + rq;                      // k within tile
        sT[row][c] = W[(size_t)(k0 + row) * 512 + n0 + c];
    }
    __syncthreads();
#pragma unroll
    for (int i = 0; i < 16; ++i) {
        const int nrow = i * 4 + rq;                     // n within tile
        const float f = sT[c][nrow];                     // bank-conflict-free
        const ushort_t h = f2b(f);
        const size_t o = (size_t)(n0 + nrow) * 512 + k0 + c;
        H[o] = h;
        if (wl) L[o] = f2b(f - b2f(h));
    }
}

// ---------------------------------------------------------------------------
// LDS-staged MFMA GEMM, K=512, tile 64x64, BK=32, 256 threads (4 waves,
// wave w owns rows 16w..16w+15 x all 64 cols).  grid = 1024: mt=gid>>3,
// nt=gid&7 (gid%8 = n-panel -> per-XCD B locality).
// 2-phase prefetch: double-buffered LDS, stage(it+1) issued before compute(it),
// single barrier/iter (its vmcnt(0) drain overlaps the whole compute phase).
// AT=float: A fp32 staged raw, hi/lo split after LDS read (NPASS=3 uses lo).
// AT=ushort_t: A bf16.  OUTMODE 0: f32.  1: bf16 hi+lo (+ fused row-norms ->
// normOut[z][t], the 64-col n-panel is exactly one head).  2: vhT[z][d][T].
// Chunk swizzle: LDS slot = (chunk + row) % nchunks -> conflict-free reads.
// ---------------------------------------------------------------------------
template <typename AT, int NPASS, int OUTMODE>
__global__ __launch_bounds__(256) void gemm_lds(
    const AT* __restrict__ A, const ushort_t* __restrict__ BTh,
    const ushort_t* __restrict__ BTl, float* __restrict__ outF,
    ushort_t* __restrict__ outH, ushort_t* __restrict__ outL,
    float* __restrict__ normOut)
{
    constexpr bool AF = (sizeof(AT) == 4);
    __shared__ __align__(16) float    sAf[AF ? 2 * 64 * 32 : 4];   // fp32 A dbuf
    __shared__ __align__(16) ushort_t sAb[AF ? 8 : 2 * 64 * 32];   // bf16 A dbuf
    __shared__ __align__(16) ushort_t sBh[2 * 64 * 32];
    __shared__ __align__(16) ushort_t sBl[NPASS == 3 ? 2 * 64 * 32 : 8];

    const int tid = threadIdx.x;
    const int w = tid >> 6, lane = tid & 63;
    const int l15 = lane & 15, quad = lane >> 4;
    const int gid = blockIdx.x;
    const int m0 = (gid >> 3) * 64, n0 = (gid & 7) * 64;

    auto STAGE = [&](int bi, int it) {
        const int k0 = it * 32;
        if constexpr (AF) {
            // A tile 64x32 f32 = 8KB: rows of 8 chunks, swizzled.
#pragma unroll
            for (int t = 0; t < 2; ++t) {
                const int c = (w * 2 + t) * 64 + lane;
                const int row = c >> 3, slot = c & 7, kch = (slot - row) & 7;
                gl_lds16((const float*)A + (size_t)(m0 + row) * 512 + k0 + kch * 4,
                         (char*)sAf + (size_t)bi * 8192 + (size_t)(w * 2 + t) * 1024);
            }
        } else {
            // A tile 64x32 bf16 = 4KB: rows of 4 chunks.
            const int c = w * 64 + lane;
            const int row = c >> 2, slot = c & 3, kch = (slot - row) & 3;
            gl_lds16((const ushort_t*)A + (size_t)(m0 + row) * 512 + k0 + kch * 8,
                     (char*)sAb + (size_t)bi * 4096 + (size_t)w * 1024);
        }
        {
            const int c = w * 64 + lane;
            const int row = c >> 2, slot = c & 3, kch = (slot - row) & 3;
            const size_t ge = (size_t)(n0 + row) * 512 + k0 + kch * 8;
            gl_lds16(BTh + ge, (char*)sBh + (size_t)bi * 4096 + (size_t)w * 1024);
            if (NPASS == 3)
                gl_lds16(BTl + ge, (char*)sBl + (size_t)bi * 4096 + (size_t)w * 1024);
        }
    };

    floatx4 acc[4];
#pragma unroll
    for (int i = 0; i < 4; ++i) acc[i] = (floatx4){0.f, 0.f, 0.f, 0.f};

    STAGE(0, 0);
    __syncthreads();
    int cur = 0;

    for (int it = 0; it < 16; ++it) {
        if (it + 1 < 16) STAGE(cur ^ 1, it + 1);   // prefetch, drains at barrier

        const float*    Af = sAf + (size_t)cur * (AF ? 64 * 32 : 0);
        const ushort_t* Ab = sAb + (size_t)cur * (AF ? 0 : 64 * 32);
        const ushort_t* Bh = sBh + (size_t)cur * (64 * 32);
        const ushort_t* Bl = sBl + (size_t)cur * (NPASS == 3 ? 64 * 32 : 0);

        // ---- fragments ----
        short8 ah, al;
        {
            const int row = 16 * w + l15;
            if constexpr (AF) {
                float4 f0 = *(const float4*)&Af[row * 32 + ((quad * 2 + row) & 7) * 4];
                float4 f1 = *(const float4*)&Af[row * 32 + ((quad * 2 + 1 + row) & 7) * 4];
                float fv[8] = {f0.x, f0.y, f0.z, f0.w, f1.x, f1.y, f1.z, f1.w};
#pragma unroll
                for (int j = 0; j < 8; ++j) {
                    ushort_t h = f2b(fv[j]);
                    ah[j] = (short)h;
                    if (NPASS == 3) al[j] = (short)f2b(fv[j] - b2f(h));
                }
            } else {
                ah = *(const short8*)&Ab[row * 32 + ((quad + row) & 3) * 8];
            }
        }
        short8 bh[4], bl[4];
#pragma unroll
        for (int ni = 0; ni < 4; ++ni) {
            const int row = ni * 16 + l15;
            const int off = row * 32 + ((quad + row) & 3) * 8;
            bh[ni] = *(const short8*)&Bh[off];
            if (NPASS == 3) bl[ni] = *(const short8*)&Bl[off];
        }
        // ---- MFMAs ----
#pragma unroll
        for (int ni = 0; ni < 4; ++ni) {
            acc[ni] = MFMA16(ah, bh[ni], acc[ni]);
            if (NPASS == 3) {
                acc[ni] = MFMA16(al, bh[ni], acc[ni]);
                acc[ni] = MFMA16(ah, bl[ni], acc[ni]);
            }
        }
        __syncthreads();
        cur ^= 1;
    }

    // ---- epilogue ----
#pragma unroll
    for (int ni = 0; ni < 4; ++ni) {
        const int n = n0 + ni * 16 + l15;
#pragma unroll
        for (int r = 0; r < 4; ++r) {
            const int m = m0 + 16 * w + quad * 4 + r;
            const float v = acc[ni][r];
            if (OUTMODE == 0) {
                outF[(size_t)m * 512 + n] = v;
            } else if (OUTMODE == 1) {
                ushort_t h = f2b(v);
                outH[(size_t)m * 512 + n] = h;
                outL[(size_t)m * 512 + n] = f2b(v - b2f(h));
            } else {
                const int b = m >> 10, t = m & 1023, hh = n >> 6, d = n & 63;
                outH[((size_t)(b * 8 + hh) * 64 + d) * 1024 + t] = f2b(v);
            }
        }
    }
    if (OUTMODE == 1) {
        // Fused per-head squared norms: cols n0..n0+63 = head (gid&7).
#pragma unroll
        for (int r = 0; r < 4; ++r) {
            float s2 = 0.f;
#pragma unroll
            for (int ni = 0; ni < 4; ++ni) s2 = fmaf(acc[ni][r], acc[ni][r], s2);
#pragma unroll
            for (int off = 1; off < 16; off <<= 1) s2 += __shfl_xor(s2, off);
            if (l15 == 0) {
                const int m = m0 + 16 * w + quad * 4 + r;
                normOut[(size_t)((m >> 10) * 8 + (gid & 7)) * 1024 + (m & 1023)] = s2;
            }
        }
    }
}

// ---------------------------------------------------------------------------
// Fused flash (R4 form): block = (z, 64 q-rows); gid = qt*64+z so gid%8==h
// (XCD L2 locality for K/V).  Per 64-col tile: stage Khi/Klo/V^T (3x8KB,
// swizzled) -> barrier -> QK 3-pass MFMA -> exp -> S store + P LDS strip
// -> SV MFMA -> barrier.  33.8KB LDS -> 4 blocks/CU (don't exceed 40KB!).
// ---------------------------------------------------------------------------
__global__ __launch_bounds__(256) void flash_rbf(
    const ushort_t* __restrict__ qh_hi, const ushort_t* __restrict__ qh_lo,
    const ushort_t* __restrict__ kh_hi, const ushort_t* __restrict__ kh_lo,
    const ushort_t* __restrict__ vhT, const float* __restrict__ q2,
    const float* __restrict__ k2, float* __restrict__ S,
    ushort_t* __restrict__ attn)
{
    __shared__ __align__(16) ushort_t sKh[64 * 64];
    __shared__ __align__(16) ushort_t sKl[64 * 64];
    __shared__ __align__(16) ushort_t sV [64 * 64];
    __shared__ __align__(16) ushort_t P  [64 * 72];

    const int tid = threadIdx.x;
    const int w = tid >> 6, lane = tid & 63;
    const int l15 = lane & 15, quad = lane >> 4;
    const int gid = blockIdx.x;
    const int z = gid & 63, qt = gid >> 6;
    const int b = z >> 3, h = z & 7;
    const int q0 = qt * 64;

    // Q fragments (registers, whole block).
    const size_t qrow = (size_t)(b * 1024 + q0 + 16 * w + l15) * 512 + h * 64 + quad * 8;
    short8 aqh[2], aql[2];
    aqh[0] = *(const short8*)(qh_hi + qrow);
    aqh[1] = *(const short8*)(qh_hi + qrow + 32);
    aql[0] = *(const short8*)(qh_lo + qrow);
    aql[1] = *(const short8*)(qh_lo + qrow + 32);

    float q2v[4];
#pragma unroll
    for (int r = 0; r < 4; ++r)
        q2v[r] = q2[(size_t)z * 1024 + q0 + 16 * w + quad * 4 + r];

    floatx4 oacc[4];
#pragma unroll
    for (int i = 0; i < 4; ++i) oacc[i] = (floatx4){0.f, 0.f, 0.f, 0.f};

    const size_t Sz = (size_t)z << 20;

    for (int ct = 0; ct < 16; ++ct) {
        const int col0 = ct * 64;

        // ---- stage K hi/lo + V^T tiles (rows of 8 chunks, swizzled) ----
#pragma unroll
        for (int t = 0; t < 2; ++t) {
            const int c = (w * 2 + t) * 64 + lane;
            const int row = c >> 3, slot = c & 7, dch = (slot - row) & 7;
            const size_t ke = (size_t)(b * 1024 + col0 + row) * 512 + h * 64 + dch * 8;
            const size_t ve = ((size_t)z * 64 + row) * 1024 + col0 + dch * 8;
            gl_lds16(kh_hi + ke, (char*)sKh + (size_t)(w * 2 + t) * 1024);
            gl_lds16(kh_lo + ke, (char*)sKl + (size_t)(w * 2 + t) * 1024);
            gl_lds16(vhT + ve,  (char*)sV  + (size_t)(w * 2 + t) * 1024);
        }
        float k2v[4];
#pragma unroll
        for (int j = 0; j < 4; ++j)
            k2v[j] = k2[(size_t)z * 1024 + col0 + j * 16 + l15];
        __syncthreads();

        // ---- QK^T, 3-pass split ----
        floatx4 s[4];
#pragma unroll
        for (int j = 0; j < 4; ++j) {
            const int row = j * 16 + l15;
            const int base = row * 64;
            short8 kh0 = *(const short8*)&sKh[base + ((quad + row) & 7) * 8];
            short8 kh1 = *(const short8*)&sKh[base + ((quad + 4 + row) & 7) * 8];
            short8 kl0 = *(const short8*)&sKl[base + ((quad + row) & 7) * 8];
            short8 kl1 = *(const short8*)&sKl[base + ((quad + 4 + row) & 7) * 8];
            s[j] = (floatx4){0.f, 0.f, 0.f, 0.f};
            s[j] = MFMA16(aqh[0], kh0, s[j]);
            s[j] = MFMA16(aqh[1], kh1, s[j]);
            s[j] = MFMA16(aql[0], kh0, s[j]);
            s[j] = MFMA16(aql[1], kh1, s[j]);
            s[j] = MFMA16(aqh[0], kl0, s[j]);
            s[j] = MFMA16(aqh[1], kl1, s[j]);
        }

        // ---- V fragments ----
        short8 gv0[4], gv1[4];
#pragma unroll
        for (int j2 = 0; j2 < 4; ++j2) {
            const int row = j2 * 16 + l15;
            const int base = row * 64;
            gv0[j2] = *(const short8*)&sV[base + ((quad + row) & 7) * 8];
            gv1[j2] = *(const short8*)&sV[base + ((quad + 4 + row) & 7) * 8];
        }

        // ---- exp, S store, P pack ----
#pragma unroll
        for (int j = 0; j < 4; ++j) {
#pragma unroll
            for (int r = 0; r < 4; ++r) {
                const float val = __expf(2.f * s[j][r] - q2v[r] - k2v[j]);
                const int row = q0 + 16 * w + quad * 4 + r;
                S[Sz + (size_t)row * 1024 + col0 + j * 16 + l15] = val;
                P[(16 * w + quad * 4 + r) * 72 + j * 16 + l15] = f2b_trunc(val);
            }
        }

        // ---- P readback (A-layout, wave-local) + S@V ----
        short8 pf0 = *(const short8*)&P[(16 * w + l15) * 72 + quad * 8];
        short8 pf1 = *(const short8*)&P[(16 * w + l15) * 72 + 32 + quad * 8];
#pragma unroll
        for (int j2 = 0; j2 < 4; ++j2) {
            oacc[j2] = MFMA16(pf0, gv0[j2], oacc[j2]);
            oacc[j2] = MFMA16(pf1, gv1[j2], oacc[j2]);
        }
        __syncthreads();
    }

#pragma unroll
    for (int j2 = 0; j2 < 4; ++j2)
#pragma unroll
        for (int r = 0; r < 4; ++r) {
            const int row = q0 + 16 * w + quad * 4 + r;
            attn[(size_t)(b * 1024 + row) * 512 + h * 64 + j2 * 16 + l15] =
                f2b(oacc[j2][r]);
        }
}

extern "C" void kernel_launch(void* const* d_in, const int* in_sizes, int n_in,
                              void* d_out, int out_size, void* d_ws, size_t ws_size,
                              hipStream_t stream)
{
    const float* query = (const float*)d_in[0];
    const float* key   = (const float*)d_in[1];
    const float* value = (const float*)d_in[2];
    const float* Wq    = (const float*)d_in[3];
    const float* Wk    = (const float*)d_in[4];
    const float* Wv    = (const float*)d_in[5];
    const float* Wo    = (const float*)d_in[6];

    float* out  = (float*)d_out;
    float* Sout = out + (size_t)8192 * 512;

    const size_t NE = (size_t)8192 * 512;
    ushort_t* qh_hi   = (ushort_t*)d_ws;
    ushort_t* qh_lo   = qh_hi + NE;
    ushort_t* kh_hi   = qh_lo + NE;
    ushort_t* kh_lo   = kh_hi + NE;
    ushort_t* vhT     = kh_lo + NE;
    ushort_t* attn_bf = vhT + NE;
    ushort_t* WqT_hi  = attn_bf + NE;
    ushort_t* WqT_lo  = WqT_hi + 262144;
    ushort_t* WkT_hi  = WqT_lo + 262144;
    ushort_t* WkT_lo  = WkT_hi + 262144;
    ushort_t* WvT     = WkT_lo + 262144;
    ushort_t* WoT     = WvT + 262144;
    float*    q2      = (float*)(WoT + 262144);
    float*    k2      = q2 + 65536;

    wt_cvt<<<dim3(64, 4), 256, 0, stream>>>(Wq, Wk, Wv, Wo, WqT_hi, WqT_lo,
                                            WkT_hi, WkT_lo, WvT, WoT);

    gemm_lds<float, 3, 1><<<1024, 256, 0, stream>>>(
        query, WqT_hi, WqT_lo, nullptr, qh_hi, qh_lo, q2);
    gemm_lds<float, 3, 1><<<1024, 256, 0, stream>>>(
        key, WkT_hi, WkT_lo, nullptr, kh_hi, kh_lo, k2);
    gemm_lds<float, 1, 2><<<1024, 256, 0, stream>>>(
        value, WvT, nullptr, nullptr, vhT, nullptr, nullptr);

    flash_rbf<<<1024, 256, 0, stream>>>(qh_hi, qh_lo, kh_hi, kh_lo,
                                        vhT, q2, k2, Sout, attn_bf);

    gemm_lds<ushort_t, 1, 0><<<1024, 256, 0, stream>>>(
        attn_bf, WoT, nullptr, out, nullptr, nullptr, nullptr);
}